// Round 3
// baseline (443.498 us; speedup 1.0000x reference)
//
#include <hip/hip_runtime.h>
#include <cstdint>

#define NPOS   32768   // B*H*W
#define KCODE  1024
#define DDIM   256
#define APITCH 40      // As row pitch (floats): 160B, 16B-aligned, 8-dword bank skew

// ---- kernel 0: wsq[k] = sum_d w[k][d]^2 ------------------------------------
__global__ void wsq_kernel(const float* __restrict__ w, float* __restrict__ wsq) {
  const int k = blockIdx.x;       // 1024
  const int lane = threadIdx.x;   // 64
  float4 v = *(const float4*)(w + (size_t)k * DDIM + lane * 4);
  float s = v.x * v.x + v.y * v.y + v.z * v.z + v.w * v.w;
  #pragma unroll
  for (int off = 32; off > 0; off >>= 1) s += __shfl_down(s, off, 64);
  if (lane == 0) wsq[k] = s;
}

__device__ __forceinline__ void fma4(float4& a, float s, const float4& b) {
  a.x = fmaf(s, b.x, a.x); a.y = fmaf(s, b.y, a.y);
  a.z = fmaf(s, b.z, a.z); a.w = fmaf(s, b.w, a.w);
}

// ---- kernel 1: fused dist-GEMM + argmin, broadcast-A -----------------------
// Block: 32 n, 256 threads (4 waves). Wave wv owns n-rows [n0+8wv, n0+8wv+8).
// Lane l covers k = j*256 + l*4 + c (j=0..3, c=0..3) -> full 1024 k per wave.
// A-reads from LDS are wave-uniform broadcasts; B-reads are contiguous b128.
__global__ __launch_bounds__(256, 2) void argmin_kernel(
    const float* __restrict__ z, const float* __restrict__ w,
    const float* __restrict__ wsq, int* __restrict__ idxout) {
  __shared__ __align__(16) float As[DDIM * APITCH];  // 40 KB, [d][n] pitch 40
  __shared__ __align__(16) float Bs[8 * KCODE];      // 32 KB, [dd][k]

  const int tid = threadIdx.x;
  const int l = tid & 63;
  const int wv = tid >> 6;            // 0..3
  const int n0 = blockIdx.x * 32;     // 1024 blocks
  const int b = n0 >> 10;
  const int hw0 = n0 & 1023;
  const float* zb = z + (size_t)b * DDIM * 1024 + hw0;

  // ---- stage A: As[d][n] (32 n per block), coalesced f4, skewed pitch ----
  {
    const int n4 = tid & 7;          // n = n4*4 .. +3
    const int d0 = tid >> 3;         // 0..31
    #pragma unroll
    for (int p = 0; p < 8; ++p) {
      const int d = p * 32 + d0;
      float4 v = *(const float4*)(zb + (size_t)d * 1024 + n4 * 4);
      *(float4*)(As + d * APITCH + n4 * 4) = v;
    }
  }

  float4 acc[32];   // acc[r*4+j].c accumulates x_n(r) . w_k, k=j*256+l*4+c
  #pragma unroll
  for (int i = 0; i < 32; ++i) acc[i] = make_float4(0.f, 0.f, 0.f, 0.f);

  const int k0 = tid * 4;                         // staging: 4 k-rows/thread
  const float* wst = w + (size_t)k0 * DDIM;

  for (int dc = 0; dc < 32; ++dc) {
    // global loads for chunk dc issued BEFORE the barrier (latency overlap)
    const float* wp = wst + dc * 8;
    float4 r0 = *(const float4*)(wp + 0 * DDIM);
    float4 r1 = *(const float4*)(wp + 0 * DDIM + 4);
    float4 r2 = *(const float4*)(wp + 1 * DDIM);
    float4 r3 = *(const float4*)(wp + 1 * DDIM + 4);
    float4 r4 = *(const float4*)(wp + 2 * DDIM);
    float4 r5 = *(const float4*)(wp + 2 * DDIM + 4);
    float4 r6 = *(const float4*)(wp + 3 * DDIM);
    float4 r7 = *(const float4*)(wp + 3 * DDIM + 4);
    __syncthreads();   // prev chunk consumed (iter 0: As staged)
    // in-register 4x4 transpose -> Bs[dd][k0..k0+3], contiguous b128 writes
    *(float4*)(Bs + 0 * KCODE + k0) = make_float4(r0.x, r2.x, r4.x, r6.x);
    *(float4*)(Bs + 1 * KCODE + k0) = make_float4(r0.y, r2.y, r4.y, r6.y);
    *(float4*)(Bs + 2 * KCODE + k0) = make_float4(r0.z, r2.z, r4.z, r6.z);
    *(float4*)(Bs + 3 * KCODE + k0) = make_float4(r0.w, r2.w, r4.w, r6.w);
    *(float4*)(Bs + 4 * KCODE + k0) = make_float4(r1.x, r3.x, r5.x, r7.x);
    *(float4*)(Bs + 5 * KCODE + k0) = make_float4(r1.y, r3.y, r5.y, r7.y);
    *(float4*)(Bs + 6 * KCODE + k0) = make_float4(r1.z, r3.z, r5.z, r7.z);
    *(float4*)(Bs + 7 * KCODE + k0) = make_float4(r1.w, r3.w, r5.w, r7.w);
    __syncthreads();   // Bs ready
    #pragma unroll
    for (int dd = 0; dd < 8; ++dd) {
      const int d = dc * 8 + dd;
      // A: wave-uniform broadcast reads (8 n-values for this wave's rows)
      float4 a0 = *(const float4*)(As + d * APITCH + wv * 8);
      float4 a1 = *(const float4*)(As + d * APITCH + wv * 8 + 4);
      // B: contiguous stride-16B b128 reads, conflict-free
      float4 b0 = *(const float4*)(Bs + dd * KCODE + 0 + l * 4);
      float4 b1 = *(const float4*)(Bs + dd * KCODE + 256 + l * 4);
      float4 b2 = *(const float4*)(Bs + dd * KCODE + 512 + l * 4);
      float4 b3 = *(const float4*)(Bs + dd * KCODE + 768 + l * 4);
      const float a[8] = {a0.x, a0.y, a0.z, a0.w, a1.x, a1.y, a1.z, a1.w};
      #pragma unroll
      for (int r = 0; r < 8; ++r) {
        fma4(acc[r * 4 + 0], a[r], b0);
        fma4(acc[r * 4 + 1], a[r], b1);
        fma4(acc[r * 4 + 2], a[r], b2);
        fma4(acc[r * 4 + 3], a[r], b3);
      }
    }
  }

  // ---- epilogue: dist = wsq[k] - 2*dot, packed-key argmin ----
  float4 wq[4];
  #pragma unroll
  for (int j = 0; j < 4; ++j) wq[j] = *(const float4*)(wsq + j * 256 + l * 4);

  unsigned long long best[8];
  #pragma unroll
  for (int r = 0; r < 8; ++r) best[r] = ~0ull;
  #pragma unroll
  for (int r = 0; r < 8; ++r) {
    #pragma unroll
    for (int j = 0; j < 4; ++j) {
      const float dq[4] = {wq[j].x - 2.f * acc[r * 4 + j].x,
                           wq[j].y - 2.f * acc[r * 4 + j].y,
                           wq[j].z - 2.f * acc[r * 4 + j].z,
                           wq[j].w - 2.f * acc[r * 4 + j].w};
      #pragma unroll
      for (int c = 0; c < 4; ++c) {
        unsigned u = __float_as_uint(dq[c]);
        u = (u & 0x80000000u) ? ~u : (u | 0x80000000u);  // monotone total order
        unsigned long long key = ((unsigned long long)u << 32)
                               | (unsigned)(j * 256 + l * 4 + c);
        best[r] = best[r] < key ? best[r] : key;         // ties -> smallest k
      }
    }
  }
  // wave-wide butterfly min (u64 shfl = 2x b32)
  #pragma unroll
  for (int off = 1; off < 64; off <<= 1) {
    #pragma unroll
    for (int r = 0; r < 8; ++r) {
      unsigned long long o = __shfl_xor(best[r], off, 64);
      best[r] = o < best[r] ? o : best[r];
    }
  }
  if (l == 0) {
    #pragma unroll
    for (int r = 0; r < 8; ++r)
      idxout[n0 + wv * 8 + r] = (int)(best[r] & 0xFFFFFFFFull);
  }
}

// ---- kernel 2: gather + permute-back, writes both outputs ------------------
__global__ void gather_kernel(const float* __restrict__ w, const int* __restrict__ idx,
                              float* __restrict__ out) {
  const int g = blockIdx.x * 256 + threadIdx.x;  // [0, 2097152) float4s
  const int hw4 = g & 255;
  const int c = (g >> 8) & 255;
  const int b = g >> 16;
  int4 kv = *(const int4*)(idx + b * 1024 + hw4 * 4);
  float4 v;
  v.x = w[(size_t)kv.x * 256 + c];
  v.y = w[(size_t)kv.y * 256 + c];
  v.z = w[(size_t)kv.z * 256 + c];
  v.w = w[(size_t)kv.w * 256 + c];
  float4* o = (float4*)out;
  o[g] = v;              // codes
  o[g + 2097152] = v;    // codes_bar (identical forward value)
}

extern "C" void kernel_launch(void* const* d_in, const int* in_sizes, int n_in,
                              void* d_out, int out_size, void* d_ws, size_t ws_size,
                              hipStream_t stream) {
  const float* z = (const float*)d_in[0];   // [32,256,32,32] fp32
  const float* w = (const float*)d_in[1];   // [1024,256] fp32
  float* out = (float*)d_out;

  float* wsq = (float*)d_ws;                 // 4KB @ 0
  int* idx = (int*)((char*)d_ws + 4096);     // 128KB @ 4KB

  wsq_kernel<<<KCODE, 64, 0, stream>>>(w, wsq);
  argmin_kernel<<<NPOS / 32, 256, 0, stream>>>(z, w, wsq, idx);
  gather_kernel<<<2097152 / 256, 256, 0, stream>>>(w, idx, out);
}

// Round 4
// 295.067 us; speedup vs baseline: 1.5030x; 1.5030x over previous
//
#include <hip/hip_runtime.h>
#include <cstdint>

#define NPOS   32768   // B*H*W
#define KCODE  1024
#define DDIM   256
#define APITCH 40      // As row pitch (floats), 16B-aligned

typedef unsigned long long u64;

// async global->LDS DMA, 16B per lane. lds pointer must be wave-uniform;
// hardware scatters lane i to lds + i*16.
__device__ __forceinline__ void async_copy16(const float* g, float* lds) {
  __builtin_amdgcn_global_load_lds(
      (const __attribute__((address_space(1))) uint32_t*)g,
      (__attribute__((address_space(3))) uint32_t*)lds, 16, 0, 0);
}

__device__ __forceinline__ void fma4(float4& a, float s, const float4& b) {
  a.x = fmaf(s, b.x, a.x); a.y = fmaf(s, b.y, a.y);
  a.z = fmaf(s, b.z, a.z); a.w = fmaf(s, b.w, a.w);
}

// ---- kernel 0: wsq[k] = sum_d w[k][d]^2 ------------------------------------
__global__ void wsq_kernel(const float* __restrict__ w, float* __restrict__ wsq) {
  const int k = blockIdx.x;       // 1024
  const int lane = threadIdx.x;   // 64
  float4 v = *(const float4*)(w + (size_t)k * DDIM + lane * 4);
  float s = v.x * v.x + v.y * v.y + v.z * v.z + v.w * v.w;
  #pragma unroll
  for (int off = 32; off > 0; off >>= 1) s += __shfl_down(s, off, 64);
  if (lane == 0) wsq[k] = s;
}

// ---- kernel 0b: wt[d][k] = w[k][d], LDS-tiled transpose --------------------
__global__ void wt_kernel(const float* __restrict__ w, float* __restrict__ wt) {
  __shared__ float T[64][65];
  const int k0 = blockIdx.x * 64;   // 16
  const int d0 = blockIdx.y * 64;   // 4
  const int c = threadIdx.x & 63;
  const int r = threadIdx.x >> 6;   // 0..3
  #pragma unroll
  for (int p = 0; p < 16; ++p) {
    const int kk = p * 4 + r;
    T[kk][c] = w[(size_t)(k0 + kk) * DDIM + d0 + c];
  }
  __syncthreads();
  #pragma unroll
  for (int p = 0; p < 16; ++p) {
    const int dd = p * 4 + r;
    wt[(size_t)(d0 + dd) * KCODE + k0 + c] = T[c][dd];
  }
}

// ---- kernel 1: fused dist-GEMM + argmin ------------------------------------
// Block: 32 n, 256 threads (4 waves). Wave (g,kh): g=wv>>1 owns 16 n-rows,
// kh=(wv&1)*512 owns a k-half. Lane l covers k = kh + j*256 + l*4 + c.
// A-reads: wave-uniform LDS broadcasts. B: contiguous b128. w chunks stream
// global->LDS via async DMA, double-buffered, one barrier per chunk; the
// barrier's vmcnt drain lands ~2000 cyc after DMA issue -> no stall.
__global__ __launch_bounds__(256, 2) void argmin_kernel(
    const float* __restrict__ z, const float* __restrict__ wt,
    const float* __restrict__ wsq, int* __restrict__ idxout) {
  __shared__ __align__(16) float As[DDIM * APITCH];   // 40 KB [d][n]
  __shared__ __align__(16) float Bs[2][4 * KCODE];    // 32 KB, chunks of 4 d
  __shared__ u64 Red[4][16];

  const int tid = threadIdx.x;
  const int l = tid & 63;
  const int wv = tid >> 6;          // 0..3
  const int ga = (wv >> 1) * 16;    // n-group base within block
  const int kh = (wv & 1) * 512;    // k-half base
  const int kl = kh + l * 4;
  const int n0 = blockIdx.x * 32;   // 1024 blocks
  const int bimg = n0 >> 10;
  const int hw0 = n0 & 1023;
  const float* zb = z + (size_t)bimg * DDIM * 1024 + hw0;

  // DMA chunk 0 -> Bs[0] (wave-uniform LDS base, lane*16B scatter)
  #pragma unroll
  for (int q = 0; q < 4; ++q)
    async_copy16(wt + q * 1024 + tid * 4, &Bs[0][0] + q * 1024 + wv * 256);

  // stage As[d][n]: thread (n4=tid&7 f4-col, d0=tid>>3), coalesced global f4
  {
    const int n4 = tid & 7;
    const int d0 = tid >> 3;
    #pragma unroll
    for (int p = 0; p < 8; ++p) {
      const int d = p * 32 + d0;
      float4 v = *(const float4*)(zb + (size_t)d * 1024 + n4 * 4);
      *(float4*)(As + d * APITCH + n4 * 4) = v;
    }
  }
  __syncthreads();   // drains own DMA (chunk0) + As writes, all waves

  float4 acc[16][2];
  #pragma unroll
  for (int n = 0; n < 16; ++n) {
    acc[n][0] = make_float4(0.f, 0.f, 0.f, 0.f);
    acc[n][1] = make_float4(0.f, 0.f, 0.f, 0.f);
  }

  #pragma unroll 1
  for (int dc = 0; dc < 64; ++dc) {
    // issue DMA for chunk dc+1 into the other buffer (its readers finished
    // at the barrier we just crossed). dc=63 wraps -> harmless reload of c0.
    {
      const int nc = (dc + 1) & 63;
      float* bn = &Bs[(dc + 1) & 1][0];
      const float* gsrc = wt + (size_t)nc * 4096;
      #pragma unroll
      for (int q = 0; q < 4; ++q)
        async_copy16(gsrc + q * 1024 + tid * 4, bn + q * 1024 + wv * 256);
    }
    // compute chunk dc
    const float* bs = &Bs[dc & 1][0];
    #pragma unroll
    for (int dd = 0; dd < 4; ++dd) {
      const float* ap = As + (dc * 4 + dd) * APITCH + ga;
      float4 a0 = *(const float4*)(ap + 0);
      float4 a1 = *(const float4*)(ap + 4);
      float4 a2 = *(const float4*)(ap + 8);
      float4 a3 = *(const float4*)(ap + 12);
      float4 b0 = *(const float4*)(bs + dd * KCODE + kl);
      float4 b1 = *(const float4*)(bs + dd * KCODE + kl + 256);
      const float a[16] = {a0.x, a0.y, a0.z, a0.w, a1.x, a1.y, a1.z, a1.w,
                           a2.x, a2.y, a2.z, a2.w, a3.x, a3.y, a3.z, a3.w};
      #pragma unroll
      for (int n = 0; n < 16; ++n) {
        fma4(acc[n][0], a[n], b0);
        fma4(acc[n][1], a[n], b1);
      }
    }
    __syncthreads();   // all waves done reading bs; own DMA (dc+1) drained
  }

  // ---- epilogue: dist = wsq[k] - 2*dot, packed-key argmin ----
  float4 wq0 = *(const float4*)(wsq + kl);
  float4 wq1 = *(const float4*)(wsq + kl + 256);
  u64 best[16];
  #pragma unroll
  for (int n = 0; n < 16; ++n) {
    const float dq[8] = {
        wq0.x - 2.f * acc[n][0].x, wq0.y - 2.f * acc[n][0].y,
        wq0.z - 2.f * acc[n][0].z, wq0.w - 2.f * acc[n][0].w,
        wq1.x - 2.f * acc[n][1].x, wq1.y - 2.f * acc[n][1].y,
        wq1.z - 2.f * acc[n][1].z, wq1.w - 2.f * acc[n][1].w};
    u64 m = ~0ull;
    #pragma unroll
    for (int j = 0; j < 2; ++j) {
      #pragma unroll
      for (int c = 0; c < 4; ++c) {
        unsigned u = __float_as_uint(dq[j * 4 + c]);
        u = (u & 0x80000000u) ? ~u : (u | 0x80000000u);  // monotone order
        u64 key = ((u64)u << 32) | (unsigned)(kh + j * 256 + l * 4 + c);
        m = m < key ? m : key;   // ties -> smallest k
      }
    }
    best[n] = m;
  }
  #pragma unroll
  for (int off = 1; off < 64; off <<= 1) {
    #pragma unroll
    for (int n = 0; n < 16; ++n) {
      u64 o = __shfl_xor((unsigned long long)best[n], off, 64);
      best[n] = o < best[n] ? o : best[n];
    }
  }
  if (l == 0) {
    #pragma unroll
    for (int n = 0; n < 16; ++n) Red[wv][n] = best[n];
  }
  __syncthreads();
  if (tid < 32) {
    const int g2 = tid >> 4, n = tid & 15;
    u64 ka = Red[g2 * 2][n], kb = Red[g2 * 2 + 1][n];
    u64 m = ka < kb ? ka : kb;
    idxout[n0 + g2 * 16 + n] = (int)(m & 0xFFFFFFFFu);
  }
}

// ---- kernel 2: gather via LDS-resident w-slice (reads wt) ------------------
// Block = (b, 16-channel slice). Ws[cc][k] staged coalesced from wt; random
// per-position reads hit LDS; writes fully coalesced f4.
#define WPITCH 1028   // 16B-aligned row pitch, offsets banks per cc
__global__ __launch_bounds__(256) void gather2_kernel(
    const float* __restrict__ wt, const int* __restrict__ idx,
    float* __restrict__ out) {
  __shared__ __align__(16) float Ws[16 * WPITCH];   // 65.8 KB
  const int tid = threadIdx.x;
  const int bimg = blockIdx.x >> 4;
  const int c0 = (blockIdx.x & 15) * 16;
  int4 kv = *(const int4*)(idx + bimg * 1024 + tid * 4);   // hw = tid*4..+3
  #pragma unroll
  for (int cc = 0; cc < 16; ++cc) {
    float4 v = *(const float4*)(wt + (size_t)(c0 + cc) * KCODE + tid * 4);
    *(float4*)(Ws + cc * WPITCH + tid * 4) = v;
  }
  __syncthreads();
  float* ob = out + (size_t)bimg * DDIM * 1024 + (size_t)c0 * 1024 + tid * 4;
  #pragma unroll
  for (int cc = 0; cc < 16; ++cc) {
    const float* wr = Ws + cc * WPITCH;
    float4 v;
    v.x = wr[kv.x]; v.y = wr[kv.y]; v.z = wr[kv.z]; v.w = wr[kv.w];
    *(float4*)(ob + (size_t)cc * 1024) = v;               // codes
    *(float4*)(ob + (size_t)cc * 1024 + 8388608) = v;     // codes_bar
  }
}

// fallback gather (no wt dependency) for tiny-workspace case
__global__ void gather_kernel(const float* __restrict__ w, const int* __restrict__ idx,
                              float* __restrict__ out) {
  const int g = blockIdx.x * 256 + threadIdx.x;
  const int hw4 = g & 255;
  const int c = (g >> 8) & 255;
  const int b = g >> 16;
  int4 kv = *(const int4*)(idx + b * 1024 + hw4 * 4);
  float4 v;
  v.x = w[(size_t)kv.x * 256 + c];
  v.y = w[(size_t)kv.y * 256 + c];
  v.z = w[(size_t)kv.z * 256 + c];
  v.w = w[(size_t)kv.w * 256 + c];
  float4* o = (float4*)out;
  o[g] = v;
  o[g + 2097152] = v;
}

extern "C" void kernel_launch(void* const* d_in, const int* in_sizes, int n_in,
                              void* d_out, int out_size, void* d_ws, size_t ws_size,
                              hipStream_t stream) {
  const float* z = (const float*)d_in[0];   // [32,256,32,32] fp32
  const float* w = (const float*)d_in[1];   // [1024,256] fp32
  float* out = (float*)d_out;

  float* wsq = (float*)d_ws;                 // 4 KB @ 0
  int* idx = (int*)((char*)d_ws + 4096);     // 128 KB @ 4 KB
  const size_t need = 4096 + 131072 + 1048576;
  const bool ws_ok = ws_size >= need;
  // wt (1 MB): workspace, else tail of d_out (argmin consumes it before the
  // fallback gather — which does NOT read wt — overwrites it).
  float* wt = ws_ok ? (float*)((char*)d_ws + 4096 + 131072)
                    : out + (size_t)out_size - 262144;

  wsq_kernel<<<KCODE, 64, 0, stream>>>(w, wsq);
  wt_kernel<<<dim3(16, 4), 256, 0, stream>>>(w, wt);
  argmin_kernel<<<NPOS / 32, 256, 0, stream>>>(z, wt, wsq, idx);
  if (ws_ok)
    gather2_kernel<<<512, 256, 0, stream>>>(wt, idx, out);
  else
    gather_kernel<<<2097152 / 256, 256, 0, stream>>>(w, idx, out);
}